// Round 11
// baseline (117.480 us; speedup 1.0000x reference)
//
#include <hip/hip_runtime.h>
#include <hip/hip_fp16.h>

#define NIN 100000
#define NOUT 50000
#define KNB 32            // neighbors per output point
#define CIN 16
#define COUT 32
#define GP 8              // points per tile (2 per wave, 4 waves)
#define ROW2B 2064        // bytes per point row in s_bl: 64*16*2 (f16) + 16 pad
#define WFOFF 65536       // feats16 offset in d_ws
#define NTILES (NOUT / GP)   // 6250
#define PBLK 1563            // persistent blocks
#define NITER 4              // tiles per block (last real tile duplicated in 2 blocks)

typedef __attribute__((ext_vector_type(8))) _Float16 half8;
typedef __attribute__((ext_vector_type(2))) _Float16 h2v;
typedef __attribute__((ext_vector_type(4))) float f32x4;

__device__ __forceinline__ h2v pmax(h2v a, h2v b) {
  h2v d;
  asm("v_pk_max_f16 %0, %1, %2" : "=v"(d) : "v"(a), "v"(b));
  return d;
}
__device__ __forceinline__ unsigned int pkh(float lo, float hi) {
  union { __half2 h; unsigned int u; } cv;
  cv.h = __floats2half2_rn(lo, hi);
  return cv.u;
}
__device__ __forceinline__ unsigned short f2hbits(float f) {
  union { __half h; unsigned short s; } c; c.h = __float2half_rn(f); return c.s;
}

// blocks 0..127: Wf[s][g][n][j] = f16(W[kc = s*32+g*8+j][n]) (GEMM2 B-frag order)
// blocks 128..: feats f32 -> f16 (only when do_feats)
__global__ void prep_kernel(const float* __restrict__ kern,
                            const float* __restrict__ feats,
                            unsigned short* __restrict__ wf,
                            unsigned short* __restrict__ f16,
                            int do_feats) {
  const int b = blockIdx.x;
  if (b < 128) {
    int idx = b * 256 + threadIdx.x;          // < 32768
    int j = idx & 7;
    int n = (idx >> 3) & 31;
    int g = (idx >> 8) & 3;
    int s = idx >> 10;
    int kc = s * 32 + g * 8 + j;
    wf[idx] = f2hbits(kern[kc * COUT + n]);
  } else if (do_feats) {
    int idx = (b - 128) * 256 + threadIdx.x;  // < 1.6e6 exactly
    f16[idx] = f2hbits(feats[idx]);
  }
}

// gather one packed f16x2 of channels c for edge pair (hh, jp) of neighbor ids nbv
#define GF(dst, nbv, hh, jp)                                                   \
  { const int n0_ = __shfl(nbv, (hh) * 32 + g * 8 + (jp) * 2);                 \
    const int n1_ = __shfl(nbv, (hh) * 32 + g * 8 + (jp) * 2 + 1);             \
    if constexpr (F16F)                                                        \
      dst = (unsigned)feats16[n0_ * CIN + c]                                   \
          | ((unsigned)feats16[n1_ * CIN + c] << 16);                          \
    else                                                                       \
      dst = pkh(featsf[n0_ * CIN + c], featsf[n1_ * CIN + c]); }

template <int F16F>
__launch_bounds__(256, 8)
__global__ void cconv_kernel(const float* __restrict__ featsf,
                             const unsigned short* __restrict__ feats16,
                             const float* __restrict__ inp_points,
                             const float* __restrict__ out_points,
                             const float* __restrict__ out_extents,
                             const float* __restrict__ scale_compat,
                             const int* __restrict__ nidx,
                             const float* __restrict__ ndist,
                             const unsigned short* __restrict__ wf,
                             const float* __restrict__ bias,
                             float* __restrict__ out) {
  // f16 B matrix; element (t,c) of point p at byte p*ROW2B + t*32 + c*2
  __shared__ __align__(16) char s_bl[GP * ROW2B];              // 16512 B
  __shared__ __align__(4) unsigned short s_tx[GP * KNB];       // 512 B each
  __shared__ __align__(4) unsigned short s_ty[GP * KNB];
  __shared__ __align__(4) unsigned short s_tz[GP * KNB];
  __shared__ __align__(4) unsigned short s_im[GP * KNB];
  __shared__ float s_cacc[GP][COUT];                           // 1024 B
  __shared__ float s_den[GP];                                  // 32 B

  const int tid = threadIdx.x;
  const int wv = tid >> 6;
  const int lane = tid & 63;
  const int c = lane & 15;          // phase-2 frag row (chan) / tap-in-tile
  const int g = lane >> 4;          // phase-2 edge group
  const int h1 = lane >> 5;         // phase-1: which of the wave's 2 points
  const int e1 = lane & 31;         // phase-1: edge within point

  ((float*)s_cacc)[tid] = 0.0f;     // blockDim == GP*COUT == 256 exactly

  int tile = blockIdx.x;

  // ---- prologue: full gather of the first tile into registers ----
  float dC, scC, pxC, pyC, pzC, oxC, oyC, ozC, invC;
  unsigned int fC0, fC1, fC2, fC3, fC4, fC5, fC6, fC7;   // fef words [h][jp]
  {
    const int e0 = tile * (GP * KNB) + tid;
    const int nb = nidx[e0];
    dC = ndist[e0];
    scC = scale_compat[e0];
    const int pg = tile * GP + wv * 2 + h1;
    oxC = out_points[pg * 3 + 0];
    oyC = out_points[pg * 3 + 1];
    ozC = out_points[pg * 3 + 2];
    invC = 1.0f / (0.5f * out_extents[pg]);
    pxC = inp_points[nb * 3 + 0];
    pyC = inp_points[nb * 3 + 1];
    pzC = inp_points[nb * 3 + 2];
    GF(fC0, nb, 0, 0) GF(fC1, nb, 0, 1) GF(fC2, nb, 0, 2) GF(fC3, nb, 0, 3)
    GF(fC4, nb, 1, 0) GF(fC5, nb, 1, 1) GF(fC6, nb, 1, 2) GF(fC7, nb, 1, 3)
  }

#pragma unroll
  for (int it = 0; it < NITER; ++it) {
    const int tnraw = tile + PBLK;
    const int tn = (tnraw < NTILES) ? tnraw : tile;   // uniform clamp (tail dup)

    // ---- A: next-tile independent streams (latency hides under phase 1+2) ----
    int nbN = 0;
    float dN = 0.f, scN = 0.f, oxN = 0.f, oyN = 0.f, ozN = 0.f, invN = 0.f;
    if (it + 1 < NITER) {             // compile-time after unroll
      const int e0n = tn * (GP * KNB) + tid;
      nbN = nidx[e0n];
      dN = ndist[e0n];
      scN = scale_compat[e0n];
      const int pgN = tn * GP + wv * 2 + h1;
      oxN = out_points[pgN * 3 + 0];
      oyN = out_points[pgN * 3 + 1];
      ozN = out_points[pgN * 3 + 2];
      invN = 1.0f / (0.5f * out_extents[pgN]);
    }

    // ---- phase 1: geometry for current tile, registers only ----
    {
      float q = 1.0f - dC * dC;
      float w6 = q * q * q;
      w6 = fminf(fmaxf(w6, 0.0f), 1.0f);
      const float imp = scC * w6;
      const float rx = (pxC - oxC) * invC;
      const float ry = (pyC - oyC) * invC;
      const float rz = (pzC - ozC) * invC;
      const float r = sqrtf(rx * rx + ry * ry + rz * rz);
      const float linf = fmaxf(fabsf(rx), fmaxf(fabsf(ry), fabsf(rz)));
      const float sf = r / fmaxf(linf, 1e-12f);
      const float tx = fminf(fmaxf((rx * sf * 0.5f + 0.5f) * 3.0f, 0.0f), 3.0f);
      const float ty = fminf(fmaxf((ry * sf * 0.5f + 0.5f) * 3.0f, 0.0f), 3.0f);
      const float tz = fminf(fmaxf((rz * sf * 0.5f + 0.5f) * 3.0f, 0.0f), 3.0f);

      // write index == tid; 2B stride -> 2 lanes/bank (free)
      s_tx[tid] = f2hbits(tx);
      s_ty[tid] = f2hbits(ty);
      s_tz[tid] = f2hbits(tz);
      s_im[tid] = f2hbits(imp);

      float dsum = imp;               // reduce within each 32-lane half
#pragma unroll
      for (int m = 1; m < 32; m <<= 1) dsum += __shfl_xor(dsum, m);
      if (e1 == 0) s_den[wv * 2 + h1] = dsum;
    }
    // NO barrier: phase 2 reads only this wave's own edge rows (same-wave
    // LDS ops execute in order).

    // ---- phase 2: per-point GEMM1 (transposed), packed-f16 hat math ----
    {
      const _Float16 kys = (_Float16)(short)(c >> 2);
      const _Float16 kzs = (_Float16)(short)(c & 3);
      const h2v z2 = {(_Float16)0, (_Float16)0};
      const h2v one2 = {(_Float16)1, (_Float16)1};
      const h2v two2 = {(_Float16)2, (_Float16)2};
      const h2v ky2 = {kys, kys};
      const h2v kz2 = {kzs, kzs};
#pragma unroll
      for (int h = 0; h < 2; ++h) {
        const int p = wv * 2 + h;
        union { unsigned int u[4]; h2v h[4]; half8 v; } wfr0, wfr1, wfr2, wfr3, fef;
        if (h == 0) {
          fef.u[0] = fC0; fef.u[1] = fC1; fef.u[2] = fC2; fef.u[3] = fC3;
        } else {
          fef.u[0] = fC4; fef.u[1] = fC5; fef.u[2] = fC6; fef.u[3] = fC7;
        }
#pragma unroll
        for (int jp = 0; jp < 4; ++jp) {     // edge pair: e = g*8 + 2jp, +1
          const int eb = p * KNB + g * 8 + jp * 2;
          const h2v tx2 = *(const h2v*)&s_tx[eb];
          const h2v ty2 = *(const h2v*)&s_ty[eb];
          const h2v tz2 = *(const h2v*)&s_tz[eb];
          const h2v im2 = *(const h2v*)&s_im[eb];
          h2v t = ty2 - ky2;
          h2v at = pmax(t, z2 - t);                  // |ty - ky|
          const h2v hy = pmax(z2, one2 - at);
          t = tz2 - kz2;
          at = pmax(t, z2 - t);
          const h2v hz = pmax(z2, one2 - at);
          const h2v m2 = hy * hz * im2;
          const h2v w0 = pmax(z2, one2 - tx2) * m2;  // tx >= 0
          t = tx2 - one2;
          at = pmax(t, z2 - t);
          const h2v w1 = pmax(z2, one2 - at) * m2;
          t = tx2 - two2;
          at = pmax(t, z2 - t);
          const h2v w2 = pmax(z2, one2 - at) * m2;
          const h2v w3 = pmax(z2, t) * m2;           // max(0, tx-2), tx <= 3
          wfr0.h[jp] = w0;
          wfr1.h[jp] = w1;
          wfr2.h[jp] = w2;
          wfr3.h[jp] = w3;
        }
        const f32x4 z = {0.f, 0.f, 0.f, 0.f};
        f32x4 d0 = __builtin_amdgcn_mfma_f32_16x16x32_f16(fef.v, wfr0.v, z, 0, 0, 0);
        f32x4 d1 = __builtin_amdgcn_mfma_f32_16x16x32_f16(fef.v, wfr1.v, z, 0, 0, 0);
        f32x4 d2 = __builtin_amdgcn_mfma_f32_16x16x32_f16(fef.v, wfr2.v, z, 0, 0, 0);
        f32x4 d3 = __builtin_amdgcn_mfma_f32_16x16x32_f16(fef.v, wfr3.v, z, 0, 0, 0);
        // lane holds chans {4g..4g+3} of tap (tile*16 + c); byte = t*32 + chan*2
        char* bp = s_bl + (unsigned)(p * ROW2B + c * 32 + g * 8);
        *(uint2*)(bp + 0 * 512) = make_uint2(pkh(d0[0], d0[1]), pkh(d0[2], d0[3]));
        *(uint2*)(bp + 1 * 512) = make_uint2(pkh(d1[0], d1[1]), pkh(d1[2], d1[3]));
        *(uint2*)(bp + 2 * 512) = make_uint2(pkh(d2[0], d2[1]), pkh(d2[2], d2[3]));
        *(uint2*)(bp + 3 * 512) = make_uint2(pkh(d3[0], d3[1]), pkh(d3[2], d3[3]));
      }
    }

    __syncthreads();   // barrier1: s_bl complete, s_cacc (re)zero visible

    // ---- C: next-tile dependent gathers; latency hides under phase 3 ----
    float pxN = 0.f, pyN = 0.f, pzN = 0.f;
    unsigned int fN0 = 0, fN1 = 0, fN2 = 0, fN3 = 0,
                 fN4 = 0, fN5 = 0, fN6 = 0, fN7 = 0;
    if (it + 1 < NITER) {             // compile-time after unroll
      pxN = inp_points[nbN * 3 + 0];
      pyN = inp_points[nbN * 3 + 1];
      pzN = inp_points[nbN * 3 + 2];
      GF(fN0, nbN, 0, 0) GF(fN1, nbN, 0, 1) GF(fN2, nbN, 0, 2) GF(fN3, nbN, 0, 3)
      GF(fN4, nbN, 1, 0) GF(fN5, nbN, 1, 1) GF(fN6, nbN, 1, 2) GF(fN7, nbN, 1, 3)
    }

    // ---- phase 3: GEMM2. M-frame 16 (8 valid), N=32, K=1024 over 4 waves ----
    f32x4 acc0 = {0.f, 0.f, 0.f, 0.f}, acc1 = {0.f, 0.f, 0.f, 0.f};
    const int pl = lane & 15;
    const int arow = pl & (GP - 1);
    const int g4 = lane >> 4;
#pragma unroll
    for (int ss = 0; ss < 8; ++ss) {
      const int s = wv * 8 + ss;
      const half8 a = *(const half8*)(s_bl + arow * ROW2B + s * 64 + g4 * 16);
      const half8 b0 = *(const half8*)(wf + ((unsigned)((s * 4 + g4) * 32) + pl) * 8);
      const half8 b1 = *(const half8*)(wf + ((unsigned)((s * 4 + g4) * 32) + 16 + pl) * 8);
      acc0 = __builtin_amdgcn_mfma_f32_16x16x32_f16(a, b0, acc0, 0, 0, 0);
      acc1 = __builtin_amdgcn_mfma_f32_16x16x32_f16(a, b1, acc1, 0, 0, 0);
    }
#pragma unroll
    for (int j = 0; j < 4; ++j) {
      const int row = g4 * 4 + j;     // D row = point; rows >= GP are duplicates
      if (row < GP) {
        atomicAdd(&s_cacc[row][pl], acc0[j]);
        atomicAdd(&s_cacc[row][pl + 16], acc1[j]);
      }
    }

    __syncthreads();   // barrier2: s_cacc complete

    // ---- epilogue: normalize, bias, relu; rezero s_cacc for next iter ----
    {
      const int p = tid >> 5;         // own-wave rows -> no barrier needed after
      const int dch = tid & 31;
      const float den = s_den[p];
      float v = ((float*)s_cacc)[tid] / (den > 0.0f ? den : 1.0f) + bias[dch];
      out[tile * (GP * COUT) + tid] = fmaxf(v, 0.0f);
      ((float*)s_cacc)[tid] = 0.0f;
    }

    // ---- rotate pipeline registers (renames after unroll) ----
    tile = tn;
    dC = dN; scC = scN;
    pxC = pxN; pyC = pyN; pzC = pzN;
    oxC = oxN; oyC = oyN; ozC = ozN; invC = invN;
    fC0 = fN0; fC1 = fN1; fC2 = fN2; fC3 = fN3;
    fC4 = fN4; fC5 = fN5; fC6 = fN6; fC7 = fN7;
  }
}

extern "C" void kernel_launch(void* const* d_in, const int* in_sizes, int n_in,
                              void* d_out, int out_size, void* d_ws, size_t ws_size,
                              hipStream_t stream) {
  const float* feats        = (const float*)d_in[0];
  const float* inp_points   = (const float*)d_in[1];
  const float* out_points   = (const float*)d_in[2];
  const float* out_extents  = (const float*)d_in[3];
  const float* scale_compat = (const float*)d_in[4];
  const int*   nidx         = (const int*)d_in[5];
  const float* ndist        = (const float*)d_in[7];
  const float* kern         = (const float*)d_in[8];
  const float* bias         = (const float*)d_in[9];
  unsigned short* wf  = (unsigned short*)d_ws;                    // 64 KiB
  unsigned short* f16 = (unsigned short*)((char*)d_ws + WFOFF);   // 3.2 MB

  const bool f16ok = ws_size >= (size_t)WFOFF + (size_t)NIN * CIN * 2;
  const int prep_blocks = 128 + (f16ok ? (NIN * CIN) / 256 : 0);
  prep_kernel<<<prep_blocks, 256, 0, stream>>>(kern, feats, wf, f16,
                                               f16ok ? 1 : 0);
  if (f16ok)
    cconv_kernel<1><<<PBLK, 256, 0, stream>>>(feats, f16, inp_points,
        out_points, out_extents, scale_compat, nidx, ndist, wf, bias,
        (float*)d_out);
  else
    cconv_kernel<0><<<PBLK, 256, 0, stream>>>(feats, f16, inp_points,
        out_points, out_extents, scale_compat, nidx, ndist, wf, bias,
        (float*)d_out);
}

// Round 12
// 97.295 us; speedup vs baseline: 1.2075x; 1.2075x over previous
//
#include <hip/hip_runtime.h>
#include <hip/hip_fp16.h>

#define NIN 100000
#define NOUT 50000
#define KNB 32            // neighbors per output point
#define CIN 16
#define COUT 32
#define GP 8              // points per tile (2 per wave, 4 waves)
#define ROW2B 2064        // bytes per point row in s_bl: 64*16*2 (f16) + 16 pad
#define EDG (NOUT * KNB)  // 1.6M edges
// d_ws layout
#define WFOFF 0
#define F16OFF 65536                       // + 3.2 MB
#define GMOFF (F16OFF + NIN * CIN * 2)     // + 12.8 MB
#define FEOFF (GMOFF + EDG * 8)            // + 51.2 MB
#define WSNEED ((size_t)FEOFF + (size_t)EDG * CIN * 2)

typedef __attribute__((ext_vector_type(8))) _Float16 half8;
typedef __attribute__((ext_vector_type(2))) _Float16 h2v;
typedef __attribute__((ext_vector_type(4))) float f32x4;

__device__ __forceinline__ h2v pmax(h2v a, h2v b) {
  h2v d;
  asm("v_pk_max_f16 %0, %1, %2" : "=v"(d) : "v"(a), "v"(b));
  return d;
}
__device__ __forceinline__ unsigned int pkh(float lo, float hi) {
  union { __half2 h; unsigned int u; } cv;
  cv.h = __floats2half2_rn(lo, hi);
  return cv.u;
}
__device__ __forceinline__ unsigned short f2hbits(float f) {
  union { __half h; unsigned short s; } c; c.h = __float2half_rn(f); return c.s;
}
__device__ __forceinline__ float hbits2f(unsigned short s) {
  union { __half h; unsigned short s; } c; c.s = s; return __half2float(c.h);
}

// blocks 0..127: Wf[s][g][n][j] = f16(W[kc = s*32+g*8+j][n]) (GEMM2 B-frag order)
// blocks 128..: feats f32 -> f16 (only when do_feats)
__global__ void prep_kernel(const float* __restrict__ kern,
                            const float* __restrict__ feats,
                            unsigned short* __restrict__ wf,
                            unsigned short* __restrict__ f16,
                            int do_feats) {
  const int b = blockIdx.x;
  if (b < 128) {
    int idx = b * 256 + threadIdx.x;          // < 32768
    int j = idx & 7;
    int n = (idx >> 3) & 31;
    int g = (idx >> 8) & 3;
    int s = idx >> 10;
    int kc = s * 32 + g * 8 + j;
    wf[idx] = f2hbits(kern[kc * COUT + n]);
  } else if (do_feats) {
    int idx = (b - 128) * 256 + threadIdx.x;  // < 1.6e6 exactly
    f16[idx] = f2hbits(feats[idx]);
  }
}

// ---- kernel A: edge-parallel geometry + feats row pre-gather. One thread =
// one edge; no LDS, no barriers, all scattered traffic lives here with full
// MLP/TLP. Writes coalesced staging: geom[e]=f16x4(tx,ty,tz,imp), fe16[e][16].
__launch_bounds__(256)
__global__ void geom_kernel(const unsigned short* __restrict__ feats16,
                            const float* __restrict__ inp_points,
                            const float* __restrict__ out_points,
                            const float* __restrict__ out_extents,
                            const float* __restrict__ scale_compat,
                            const int* __restrict__ nidx,
                            const float* __restrict__ ndist,
                            uint2* __restrict__ geom,
                            unsigned short* __restrict__ fe16) {
  const int e = blockIdx.x * 256 + threadIdx.x;   // < EDG exactly
  const int p = e >> 5;                            // output point
  const int nb = nidx[e];

  // feats row copy (scattered read, coalesced write) — issue first for MLP
  const uint4 r0 = *(const uint4*)(feats16 + nb * CIN);
  const uint4 r1 = *(const uint4*)(feats16 + nb * CIN + 8);

  const float d = ndist[e];
  float q = 1.0f - d * d;
  float w6 = q * q * q;
  w6 = fminf(fmaxf(w6, 0.0f), 1.0f);
  const float imp = scale_compat[e] * w6;

  const float inv = 1.0f / (0.5f * out_extents[p]);
  const float rx = (inp_points[nb * 3 + 0] - out_points[p * 3 + 0]) * inv;
  const float ry = (inp_points[nb * 3 + 1] - out_points[p * 3 + 1]) * inv;
  const float rz = (inp_points[nb * 3 + 2] - out_points[p * 3 + 2]) * inv;
  const float r = sqrtf(rx * rx + ry * ry + rz * rz);
  const float linf = fmaxf(fabsf(rx), fmaxf(fabsf(ry), fabsf(rz)));
  const float sf = r / fmaxf(linf, 1e-12f);
  const float tx = fminf(fmaxf((rx * sf * 0.5f + 0.5f) * 3.0f, 0.0f), 3.0f);
  const float ty = fminf(fmaxf((ry * sf * 0.5f + 0.5f) * 3.0f, 0.0f), 3.0f);
  const float tz = fminf(fmaxf((rz * sf * 0.5f + 0.5f) * 3.0f, 0.0f), 3.0f);

  geom[e] = make_uint2(pkh(tx, ty), pkh(tz, imp));
  *(uint4*)(fe16 + e * CIN) = r0;
  *(uint4*)(fe16 + e * CIN + 8) = r1;
}

// ---- kernel B: tile-parallel GEMM. ALL loads coalesced from staging; the
// phase-2/3 math is byte-identical to the R10 kernel. ----
__launch_bounds__(256, 8)
__global__ void tile_kernel(const uint2* __restrict__ geom,
                            const unsigned short* __restrict__ fe16,
                            const unsigned short* __restrict__ wf,
                            const float* __restrict__ bias,
                            float* __restrict__ out) {
  __shared__ __align__(16) char s_bl[GP * ROW2B];              // 16512 B
  __shared__ __align__(4) unsigned short s_tx[GP * KNB];       // 512 B each
  __shared__ __align__(4) unsigned short s_ty[GP * KNB];
  __shared__ __align__(4) unsigned short s_tz[GP * KNB];
  __shared__ __align__(4) unsigned short s_im[GP * KNB];
  __shared__ float s_cacc[GP][COUT];                           // 1024 B
  __shared__ float s_den[GP];                                  // 32 B

  const int tid = threadIdx.x;
  const int wv = tid >> 6;
  const int lane = tid & 63;
  const int c = lane & 15;          // phase-2 frag row (chan) / tap-in-tile
  const int g = lane >> 4;          // phase-2 edge group

  ((float*)s_cacc)[tid] = 0.0f;     // blockDim == GP*COUT == 256 exactly

  // ---- phase 0: fully coalesced staging. tid == edge-in-block. ----
  {
    const int e0 = blockIdx.x * (GP * KNB) + tid;
    const uint2 gm = geom[e0];
    const uint4 q0 = *(const uint4*)(fe16 + e0 * CIN);
    const uint4 q1 = *(const uint4*)(fe16 + e0 * CIN + 8);

    s_tx[tid] = (unsigned short)(gm.x & 0xffffu);
    s_ty[tid] = (unsigned short)(gm.x >> 16);
    s_tz[tid] = (unsigned short)(gm.y & 0xffffu);
    s_im[tid] = (unsigned short)(gm.y >> 16);

    const int p = tid >> 5;         // point-in-block == wv*2 + (lane>>5)
    const int e2 = tid & 31;        // edge-within-point
    *(uint4*)(s_bl + p * ROW2B + e2 * 32) = q0;
    *(uint4*)(s_bl + p * ROW2B + e2 * 32 + 16) = q1;

    float dsum = hbits2f((unsigned short)(gm.y >> 16));
#pragma unroll
    for (int m = 1; m < 32; m <<= 1) dsum += __shfl_xor(dsum, m);
    if (e2 == 0) s_den[p] = dsum;
  }
  // NO barrier: phase 2 reads only this wave's own rows (same-wave LDS order).

  // ---- phase 2: per-point GEMM1 (transposed), packed-f16 2-wide hat math ----
  {
    const _Float16 kys = (_Float16)(short)(c >> 2);
    const _Float16 kzs = (_Float16)(short)(c & 3);
    const h2v z2 = {(_Float16)0, (_Float16)0};
    const h2v one2 = {(_Float16)1, (_Float16)1};
    const h2v two2 = {(_Float16)2, (_Float16)2};
    const h2v ky2 = {kys, kys};
    const h2v kz2 = {kzs, kzs};
#pragma unroll
    for (int h = 0; h < 2; ++h) {
      const int p = wv * 2 + h;
      union { unsigned int u[4]; h2v h[4]; half8 v; } wfr0, wfr1, wfr2, wfr3, fef;
      // fef from staged rows (consumed before this row's D1 writes land)
#pragma unroll
      for (int jp = 0; jp < 4; ++jp) {
        const unsigned a0 = (unsigned)(p * ROW2B + (g * 8 + jp * 2) * 32 + c * 2);
        const unsigned short lo = *(const unsigned short*)(s_bl + a0);
        const unsigned short hi = *(const unsigned short*)(s_bl + a0 + 32);
        fef.u[jp] = (unsigned)lo | ((unsigned)hi << 16);
      }
#pragma unroll
      for (int jp = 0; jp < 4; ++jp) {       // edge pair: e = g*8 + 2jp, +1
        const int eb = p * KNB + g * 8 + jp * 2;
        const h2v tx2 = *(const h2v*)&s_tx[eb];
        const h2v ty2 = *(const h2v*)&s_ty[eb];
        const h2v tz2 = *(const h2v*)&s_tz[eb];
        const h2v im2 = *(const h2v*)&s_im[eb];
        h2v t = ty2 - ky2;
        h2v at = pmax(t, z2 - t);                    // |ty - ky|
        const h2v hy = pmax(z2, one2 - at);
        t = tz2 - kz2;
        at = pmax(t, z2 - t);
        const h2v hz = pmax(z2, one2 - at);
        const h2v m2 = hy * hz * im2;
        const h2v w0 = pmax(z2, one2 - tx2) * m2;    // tx >= 0
        t = tx2 - one2;
        at = pmax(t, z2 - t);
        const h2v w1 = pmax(z2, one2 - at) * m2;
        t = tx2 - two2;
        at = pmax(t, z2 - t);
        const h2v w2 = pmax(z2, one2 - at) * m2;
        const h2v w3 = pmax(z2, t) * m2;             // max(0, tx-2), tx <= 3
        wfr0.h[jp] = w0;
        wfr1.h[jp] = w1;
        wfr2.h[jp] = w2;
        wfr3.h[jp] = w3;
      }
      const f32x4 z = {0.f, 0.f, 0.f, 0.f};
      f32x4 d0 = __builtin_amdgcn_mfma_f32_16x16x32_f16(fef.v, wfr0.v, z, 0, 0, 0);
      f32x4 d1 = __builtin_amdgcn_mfma_f32_16x16x32_f16(fef.v, wfr1.v, z, 0, 0, 0);
      f32x4 d2 = __builtin_amdgcn_mfma_f32_16x16x32_f16(fef.v, wfr2.v, z, 0, 0, 0);
      f32x4 d3 = __builtin_amdgcn_mfma_f32_16x16x32_f16(fef.v, wfr3.v, z, 0, 0, 0);
      // lane holds chans {4g..4g+3} of tap (tile*16 + c); byte = t*32 + chan*2
      char* bp = s_bl + (unsigned)(p * ROW2B + c * 32 + g * 8);
      *(uint2*)(bp + 0 * 512) = make_uint2(pkh(d0[0], d0[1]), pkh(d0[2], d0[3]));
      *(uint2*)(bp + 1 * 512) = make_uint2(pkh(d1[0], d1[1]), pkh(d1[2], d1[3]));
      *(uint2*)(bp + 2 * 512) = make_uint2(pkh(d2[0], d2[1]), pkh(d2[2], d2[3]));
      *(uint2*)(bp + 3 * 512) = make_uint2(pkh(d3[0], d3[1]), pkh(d3[2], d3[3]));
    }
  }

  __syncthreads();

  // ---- phase 3: GEMM2. M-frame 16 (8 valid points), N = 32, K = 1024 over
  // 4 waves (8 ksteps of 32 each); A-frag is a raw b128 f16 read. ----
  f32x4 acc0 = {0.f, 0.f, 0.f, 0.f}, acc1 = {0.f, 0.f, 0.f, 0.f};
  const int pl = lane & 15;
  const int arow = pl & (GP - 1);
  const int g4 = lane >> 4;
#pragma unroll
  for (int ss = 0; ss < 8; ++ss) {
    const int s = wv * 8 + ss;
    const half8 a = *(const half8*)(s_bl + arow * ROW2B + s * 64 + g4 * 16);
    const half8 b0 = *(const half8*)(wf + ((unsigned)((s * 4 + g4) * 32) + pl) * 8);
    const half8 b1 = *(const half8*)(wf + ((unsigned)((s * 4 + g4) * 32) + 16 + pl) * 8);
    acc0 = __builtin_amdgcn_mfma_f32_16x16x32_f16(a, b0, acc0, 0, 0, 0);
    acc1 = __builtin_amdgcn_mfma_f32_16x16x32_f16(a, b1, acc1, 0, 0, 0);
  }
#pragma unroll
  for (int j = 0; j < 4; ++j) {
    const int row = g4 * 4 + j;
    if (row < GP) {
      atomicAdd(&s_cacc[row][pl], acc0[j]);
      atomicAdd(&s_cacc[row][pl + 16], acc1[j]);
    }
  }

  __syncthreads();

  // ---- epilogue ----
  {
    const int p = tid >> 5;
    const int dch = tid & 31;
    const float den = s_den[p];
    float v = ((float*)s_cacc)[tid] / (den > 0.0f ? den : 1.0f) + bias[dch];
    out[blockIdx.x * (GP * COUT) + tid] = fmaxf(v, 0.0f);
  }
}

// ---- fallback: R10 monolith (used only if ws_size is too small) ----
#define GF(dst, nbv, hh, jp)                                                   \
  { const int n0_ = __shfl(nbv, (hh) * 32 + g * 8 + (jp) * 2);                 \
    const int n1_ = __shfl(nbv, (hh) * 32 + g * 8 + (jp) * 2 + 1);             \
    if constexpr (F16F)                                                        \
      dst = (unsigned)feats16[n0_ * CIN + c]                                   \
          | ((unsigned)feats16[n1_ * CIN + c] << 16);                          \
    else                                                                       \
      dst = pkh(featsf[n0_ * CIN + c], featsf[n1_ * CIN + c]); }

template <int F16F>
__launch_bounds__(256, 8)
__global__ void cconv_kernel(const float* __restrict__ featsf,
                             const unsigned short* __restrict__ feats16,
                             const float* __restrict__ inp_points,
                             const float* __restrict__ out_points,
                             const float* __restrict__ out_extents,
                             const float* __restrict__ scale_compat,
                             const int* __restrict__ nidx,
                             const float* __restrict__ ndist,
                             const unsigned short* __restrict__ wf,
                             const float* __restrict__ bias,
                             float* __restrict__ out) {
  __shared__ __align__(16) char s_bl[GP * ROW2B];
  __shared__ __align__(4) unsigned short s_tx[GP * KNB];
  __shared__ __align__(4) unsigned short s_ty[GP * KNB];
  __shared__ __align__(4) unsigned short s_tz[GP * KNB];
  __shared__ __align__(4) unsigned short s_im[GP * KNB];
  __shared__ float s_cacc[GP][COUT];
  __shared__ float s_den[GP];

  const int tid = threadIdx.x;
  const int wv = tid >> 6;
  const int lane = tid & 63;
  const int c = lane & 15;
  const int g = lane >> 4;

  ((float*)s_cacc)[tid] = 0.0f;

  const int eg0 = blockIdx.x * (GP * KNB) + tid;
  const int my_nb = nidx[eg0];
  const float my_d = ndist[eg0];
  const float my_sc = scale_compat[eg0];
  unsigned int fp[8];
#pragma unroll
  for (int h = 0; h < 2; ++h) {
    GF(fp[h * 4 + 0], my_nb, h, 0) GF(fp[h * 4 + 1], my_nb, h, 1)
    GF(fp[h * 4 + 2], my_nb, h, 2) GF(fp[h * 4 + 3], my_nb, h, 3)
  }
  {
    const int h = lane >> 5;
    const int e = lane & 31;
    const int p = wv * 2 + h;
    const int pg = blockIdx.x * GP + p;
    float q = 1.0f - my_d * my_d;
    float w6 = q * q * q;
    w6 = fminf(fmaxf(w6, 0.0f), 1.0f);
    const float imp = my_sc * w6;
    const float inv = 1.0f / (0.5f * out_extents[pg]);
    const float rx = (inp_points[my_nb * 3 + 0] - out_points[pg * 3 + 0]) * inv;
    const float ry = (inp_points[my_nb * 3 + 1] - out_points[pg * 3 + 1]) * inv;
    const float rz = (inp_points[my_nb * 3 + 2] - out_points[pg * 3 + 2]) * inv;
    const float r = sqrtf(rx * rx + ry * ry + rz * rz);
    const float linf = fmaxf(fabsf(rx), fmaxf(fabsf(ry), fabsf(rz)));
    const float sf = r / fmaxf(linf, 1e-12f);
    const float tx = fminf(fmaxf((rx * sf * 0.5f + 0.5f) * 3.0f, 0.0f), 3.0f);
    const float ty = fminf(fmaxf((ry * sf * 0.5f + 0.5f) * 3.0f, 0.0f), 3.0f);
    const float tz = fminf(fmaxf((rz * sf * 0.5f + 0.5f) * 3.0f, 0.0f), 3.0f);
    s_tx[tid] = f2hbits(tx);
    s_ty[tid] = f2hbits(ty);
    s_tz[tid] = f2hbits(tz);
    s_im[tid] = f2hbits(imp);
    float dsum = imp;
#pragma unroll
    for (int m = 1; m < 32; m <<= 1) dsum += __shfl_xor(dsum, m);
    if (e == 0) s_den[p] = dsum;
  }
  {
    const _Float16 kys = (_Float16)(short)(c >> 2);
    const _Float16 kzs = (_Float16)(short)(c & 3);
    const h2v z2 = {(_Float16)0, (_Float16)0};
    const h2v one2 = {(_Float16)1, (_Float16)1};
    const h2v two2 = {(_Float16)2, (_Float16)2};
    const h2v ky2 = {kys, kys};
    const h2v kz2 = {kzs, kzs};
#pragma unroll
    for (int h = 0; h < 2; ++h) {
      const int p = wv * 2 + h;
      union { unsigned int u[4]; h2v h[4]; half8 v; } wfr0, wfr1, wfr2, wfr3, fef;
      fef.u[0] = fp[h * 4 + 0]; fef.u[1] = fp[h * 4 + 1];
      fef.u[2] = fp[h * 4 + 2]; fef.u[3] = fp[h * 4 + 3];
#pragma unroll
      for (int jp = 0; jp < 4; ++jp) {
        const int eb = p * KNB + g * 8 + jp * 2;
        const h2v tx2 = *(const h2v*)&s_tx[eb];
        const h2v ty2 = *(const h2v*)&s_ty[eb];
        const h2v tz2 = *(const h2v*)&s_tz[eb];
        const h2v im2 = *(const h2v*)&s_im[eb];
        h2v t = ty2 - ky2;
        h2v at = pmax(t, z2 - t);
        const h2v hy = pmax(z2, one2 - at);
        t = tz2 - kz2;
        at = pmax(t, z2 - t);
        const h2v hz = pmax(z2, one2 - at);
        const h2v m2 = hy * hz * im2;
        const h2v w0 = pmax(z2, one2 - tx2) * m2;
        t = tx2 - one2;
        at = pmax(t, z2 - t);
        const h2v w1 = pmax(z2, one2 - at) * m2;
        t = tx2 - two2;
        at = pmax(t, z2 - t);
        const h2v w2 = pmax(z2, one2 - at) * m2;
        const h2v w3 = pmax(z2, t) * m2;
        wfr0.h[jp] = w0; wfr1.h[jp] = w1; wfr2.h[jp] = w2; wfr3.h[jp] = w3;
      }
      const f32x4 z = {0.f, 0.f, 0.f, 0.f};
      f32x4 d0 = __builtin_amdgcn_mfma_f32_16x16x32_f16(fef.v, wfr0.v, z, 0, 0, 0);
      f32x4 d1 = __builtin_amdgcn_mfma_f32_16x16x32_f16(fef.v, wfr1.v, z, 0, 0, 0);
      f32x4 d2 = __builtin_amdgcn_mfma_f32_16x16x32_f16(fef.v, wfr2.v, z, 0, 0, 0);
      f32x4 d3 = __builtin_amdgcn_mfma_f32_16x16x32_f16(fef.v, wfr3.v, z, 0, 0, 0);
      char* bp = s_bl + (unsigned)(p * ROW2B + c * 32 + g * 8);
      *(uint2*)(bp + 0 * 512) = make_uint2(pkh(d0[0], d0[1]), pkh(d0[2], d0[3]));
      *(uint2*)(bp + 1 * 512) = make_uint2(pkh(d1[0], d1[1]), pkh(d1[2], d1[3]));
      *(uint2*)(bp + 2 * 512) = make_uint2(pkh(d2[0], d2[1]), pkh(d2[2], d2[3]));
      *(uint2*)(bp + 3 * 512) = make_uint2(pkh(d3[0], d3[1]), pkh(d3[2], d3[3]));
    }
  }
  __syncthreads();
  f32x4 acc0 = {0.f, 0.f, 0.f, 0.f}, acc1 = {0.f, 0.f, 0.f, 0.f};
  const int pl = lane & 15;
  const int arow = pl & (GP - 1);
  const int g4 = lane >> 4;
#pragma unroll
  for (int ss = 0; ss < 8; ++ss) {
    const int s = wv * 8 + ss;
    const half8 a = *(const half8*)(s_bl + arow * ROW2B + s * 64 + g4 * 16);
    const half8 b0 = *(const half8*)(wf + ((unsigned)((s * 4 + g4) * 32) + pl) * 8);
    const half8 b1 = *(const half8*)(wf + ((unsigned)((s * 4 + g4) * 32) + 16 + pl) * 8);
    acc0 = __builtin_amdgcn_mfma_f32_16x16x32_f16(a, b0, acc0, 0, 0, 0);
    acc1 = __builtin_amdgcn_mfma_f32_16x16x32_f16(a, b1, acc1, 0, 0, 0);
  }
#pragma unroll
  for (int j = 0; j < 4; ++j) {
    const int row = g4 * 4 + j;
    if (row < GP) {
      atomicAdd(&s_cacc[row][pl], acc0[j]);
      atomicAdd(&s_cacc[row][pl + 16], acc1[j]);
    }
  }
  __syncthreads();
  {
    const int p = tid >> 5;
    const int dch = tid & 31;
    const float den = s_den[p];
    float v = ((float*)s_cacc)[tid] / (den > 0.0f ? den : 1.0f) + bias[dch];
    out[blockIdx.x * (GP * COUT) + tid] = fmaxf(v, 0.0f);
  }
}

extern "C" void kernel_launch(void* const* d_in, const int* in_sizes, int n_in,
                              void* d_out, int out_size, void* d_ws, size_t ws_size,
                              hipStream_t stream) {
  const float* feats        = (const float*)d_in[0];
  const float* inp_points   = (const float*)d_in[1];
  const float* out_points   = (const float*)d_in[2];
  const float* out_extents  = (const float*)d_in[3];
  const float* scale_compat = (const float*)d_in[4];
  const int*   nidx         = (const int*)d_in[5];
  const float* ndist        = (const float*)d_in[7];
  const float* kern         = (const float*)d_in[8];
  const float* bias         = (const float*)d_in[9];
  unsigned short* wf  = (unsigned short*)d_ws;
  unsigned short* f16 = (unsigned short*)((char*)d_ws + F16OFF);
  uint2*          gm  = (uint2*)((char*)d_ws + GMOFF);
  unsigned short* fe  = (unsigned short*)((char*)d_ws + FEOFF);

  const bool f16ok = ws_size >= (size_t)F16OFF + (size_t)NIN * CIN * 2;
  const bool split = ws_size >= WSNEED;
  const int prep_blocks = 128 + (f16ok ? (NIN * CIN) / 256 : 0);
  prep_kernel<<<prep_blocks, 256, 0, stream>>>(kern, feats, wf, f16,
                                               f16ok ? 1 : 0);
  if (split) {
    geom_kernel<<<EDG / 256, 256, 0, stream>>>(f16, inp_points, out_points,
                                               out_extents, scale_compat,
                                               nidx, ndist, gm, fe);
    tile_kernel<<<NOUT / GP, 256, 0, stream>>>(gm, fe, wf, bias, (float*)d_out);
  } else if (f16ok) {
    cconv_kernel<1><<<NOUT / GP, 256, 0, stream>>>(feats, f16, inp_points,
        out_points, out_extents, scale_compat, nidx, ndist, wf, bias,
        (float*)d_out);
  } else {
    cconv_kernel<0><<<NOUT / GP, 256, 0, stream>>>(feats, f16, inp_points,
        out_points, out_extents, scale_compat, nidx, ndist, wf, bias,
        (float*)d_out);
  }
}